// Round 1
// baseline (599.251 us; speedup 1.0000x reference)
//
#include <hip/hip_runtime.h>
#include <hip/hip_fp16.h>

// VQ codebook argmin: N=32768 queries x K=8192 codes x D=256 fp32.
// Strategy: f16 hi/lo split (3 MFMA terms) => fp32-accurate dots on the
// 2.5PF matrix pipe; fused running argmin; XOR-swizzled LDS staging via
// global_load_lds(16B) to keep ds_read_b128 conflict-free.
//
// Scaling (exact powers of 2, argmin-invariant): z*=2^4, e*=2^15, so f16
// "lo" parts avoid fp16 subnormal flush. dist_scaled = 2^19*cb_sq - 2*acc.
//
// R2: software-pipelined staging (T3 minimum 2-phase recipe). 32-wide
// k-chunks double-buffered (66KB LDS keeps 2 blocks/CU); per stage:
// issue next stage's global_load_lds -> ds_read frags -> 48 MFMA
// (setprio-wrapped) -> s_waitcnt vmcnt(0) -> s_barrier. Removes the
// __syncthreads() vmcnt(0) drain that serialized staging vs compute.
// New swizzle for 64B rows: slot = quad ^ ((row>>1)&3) (2-way = free).

#define N_Q   32768
#define K_CB  8192
#define D_DIM 256

typedef _Float16 half8 __attribute__((ext_vector_type(8)));
typedef _Float16 half4 __attribute__((ext_vector_type(4)));
typedef float    f32x4 __attribute__((ext_vector_type(4)));

__device__ __forceinline__ void gl_lds16(const _Float16* g, _Float16* l) {
  __builtin_amdgcn_global_load_lds(
      (const __attribute__((address_space(1))) unsigned int*)g,
      (__attribute__((address_space(3))) unsigned int*)l, 16, 0, 0);
}

// ---------------- prep: z -> (hi,lo) f16, scale 2^4 ----------------
__global__ void vq_prep_z(const float* __restrict__ z,
                          _Float16* __restrict__ zh, _Float16* __restrict__ zl) {
  int i = blockIdx.x * 256 + threadIdx.x;          // 2,097,152 float4 groups
  float4 v = ((const float4*)z)[i];
  float xs[4] = {v.x * 16.0f, v.y * 16.0f, v.z * 16.0f, v.w * 16.0f};
  half4 h, l;
#pragma unroll
  for (int j = 0; j < 4; ++j) {
    _Float16 hj = (_Float16)xs[j];
    h[j] = hj;
    l[j] = (_Float16)(xs[j] - (float)hj);
  }
  ((half4*)zh)[i] = h;
  ((half4*)zl)[i] = l;
}

// ------- prep: codebook -> (hi,lo) f16 scale 2^15, plus 2^19*||e||^2 -------
__global__ void vq_prep_cb(const float* __restrict__ cb,
                           _Float16* __restrict__ eh, _Float16* __restrict__ el,
                           float* __restrict__ cbs) {
  int w = threadIdx.x >> 6, lane = threadIdx.x & 63;
  int code = blockIdx.x * 4 + w;                   // wave per code
  float4 v = ((const float4*)cb)[code * 64 + lane];
  float ss = v.x * v.x + v.y * v.y + v.z * v.z + v.w * v.w; // unscaled, like ref
  float xs[4] = {v.x * 32768.0f, v.y * 32768.0f, v.z * 32768.0f, v.w * 32768.0f};
  half4 h, l;
#pragma unroll
  for (int j = 0; j < 4; ++j) {
    _Float16 hj = (_Float16)xs[j];
    h[j] = hj;
    l[j] = (_Float16)(xs[j] - (float)hj);
  }
  ((half4*)eh)[code * 64 + lane] = h;
  ((half4*)el)[code * 64 + lane] = l;
#pragma unroll
  for (int off = 1; off < 64; off <<= 1) ss += __shfl_xor(ss, off);
  if (lane == 0) cbs[code] = ss * 524288.0f;       // 2^19 scale matches dot scale
}

// ---------------- main: fused GEMM + running argmin ----------------
// Block: 256 thr = 4 waves (2x2), tile 128 queries x 128 codes per ct-iter.
// Grid: 256 query-tiles x 2 K-splits = 512 blocks (2/CU at 66KB LDS).
// K-loop: 8 stages/ct of 32 k-cols, double-buffered, 1 raw barrier/stage.
__global__ __launch_bounds__(256, 2)
void vq_main(const _Float16* __restrict__ zh, const _Float16* __restrict__ zl,
             const _Float16* __restrict__ eh, const _Float16* __restrict__ el,
             const float* __restrict__ cbs,
             unsigned long long* __restrict__ partials) {
  // Per stage-buffer: 128 rows x 32 k f16 = 8KB. [2] = double buffer.
  __shared__ __align__(16) _Float16 Ah[2][4096], Al[2][4096];
  __shared__ __align__(16) _Float16 Bh[2][4096], Bl[2][4096];
  __shared__ float    redD[2][128];
  __shared__ unsigned redC[2][128];

  const int tid  = threadIdx.x;
  const int lane = tid & 63;
  const int w    = tid >> 6;
  const int q    = lane & 15;
  const int quad = lane >> 4;
  const int wrow = (w >> 1) * 64;   // wave's query-row base in tile
  const int wcol = (w & 1) * 64;    // wave's code-col base in tile

  const int qt    = blockIdx.x >> 1;
  const int split = blockIdx.x & 1;
  const int q0    = qt * 128;
  const int c0    = split * 4096;

  // Staging geometry: 512 x 16B slots per buffer; thread owns 2 slots.
  // Physical slot p: row = p>>2, sl = p&3; data = k-chunk (sl ^ ((row>>1)&3)).
  // Written linearly by gl_lds (wave base + lane*16), swizzle via GLOBAL src.
  int srow[2], sgq[2], ldst[2];
#pragma unroll
  for (int c = 0; c < 2; ++c) {
    int p   = (w * 2 + c) * 64 + lane;
    srow[c] = p >> 2;
    sgq[c]  = (p & 3) ^ ((srow[c] >> 1) & 3);
    ldst[c] = (w * 2 + c) * 512;        // f16 elems (1KB chunk per wave-slot)
  }

  // Fragment LDS offsets (f16 elems): row*32 + (quad ^ ((row>>1)&3))*8.
  // (row>>1)&3 == (q>>1)&3 since wrow+mt*16 is a multiple of 16.
  const int sw = (quad ^ ((q >> 1) & 3)) << 3;
  int offA[4], offB[4];
#pragma unroll
  for (int mt = 0; mt < 4; ++mt) {
    offA[mt] = (wrow + mt * 16 + q) * 32 + sw;
    offB[mt] = (wcol + mt * 16 + q) * 32 + sw;
  }

  float    rd[16];
  unsigned rc[16];
#pragma unroll
  for (int i = 0; i < 16; ++i) { rd[i] = 3.0e38f; rc[i] = 0u; }

  // Issue one stage's 8 global_load_lds (A/B hi/lo, 32KB total per block).
  auto STAGE = [&](int sct, int skc, int pb) {
    const int    kcol  = skc * 32;
    const size_t abase = (size_t)q0 * 256 + kcol;
    const size_t bbase = (size_t)(c0 + sct * 128) * 256 + kcol;
#pragma unroll
    for (int c = 0; c < 2; ++c) {
      int goff = srow[c] * 256 + sgq[c] * 8;
      gl_lds16(zh + abase + goff, &Ah[pb][ldst[c]]);
      gl_lds16(zl + abase + goff, &Al[pb][ldst[c]]);
      gl_lds16(eh + bbase + goff, &Bh[pb][ldst[c]]);
      gl_lds16(el + bbase + goff, &Bl[pb][ldst[c]]);
    }
  };

  // Prologue: stage (ct=0, kc=0) into buffer 0.
  STAGE(0, 0, 0);
  asm volatile("s_waitcnt vmcnt(0)" ::: "memory");
  __builtin_amdgcn_s_barrier();
  __builtin_amdgcn_sched_barrier(0);

  for (int ct = 0; ct < 32; ++ct) {
    const int crow0 = c0 + ct * 128;
    f32x4 acc[4][4];
#pragma unroll
    for (int mt = 0; mt < 4; ++mt)
#pragma unroll
      for (int nt = 0; nt < 4; ++nt)
        acc[mt][nt] = (f32x4){0.f, 0.f, 0.f, 0.f};

#pragma unroll
    for (int kc = 0; kc < 8; ++kc) {
      const int pb = kc & 1;            // stage parity: global s = ct*8+kc, 8 even
      // Issue NEXT stage's loads first: they complete under this stage's MFMA.
      if (ct < 31 || kc < 7) {
        const int ns = ct * 8 + kc + 1;
        STAGE(ns >> 3, ns & 7, pb ^ 1);
      }

      half8 ahf[4], alf[4], bhf[4], blf[4];
#pragma unroll
      for (int i = 0; i < 4; ++i) {
        ahf[i] = *(const half8*)&Ah[pb][offA[i]];
        alf[i] = *(const half8*)&Al[pb][offA[i]];
        bhf[i] = *(const half8*)&Bh[pb][offB[i]];
        blf[i] = *(const half8*)&Bl[pb][offB[i]];
      }

      __builtin_amdgcn_s_setprio(1);
#pragma unroll
      for (int mt = 0; mt < 4; ++mt)
#pragma unroll
        for (int nt = 0; nt < 4; ++nt) {
          acc[mt][nt] = __builtin_amdgcn_mfma_f32_16x16x32_f16(ahf[mt], bhf[nt], acc[mt][nt], 0, 0, 0);
          acc[mt][nt] = __builtin_amdgcn_mfma_f32_16x16x32_f16(ahf[mt], blf[nt], acc[mt][nt], 0, 0, 0);
          acc[mt][nt] = __builtin_amdgcn_mfma_f32_16x16x32_f16(alf[mt], bhf[nt], acc[mt][nt], 0, 0, 0);
        }
      __builtin_amdgcn_s_setprio(0);

      // Next stage's loads must be LDS-resident before any wave reads them.
      asm volatile("s_waitcnt vmcnt(0)" ::: "memory");
      __builtin_amdgcn_s_barrier();
      __builtin_amdgcn_sched_barrier(0);
    }

    // Epilogue: dist = 2^19*cb_sq - 2*acc; running (min,idx) per row.
    // Overlaps the already-issued staging of next ct's first chunk.
    const int cb0 = crow0 + wcol + q;
    float cbsv[4];
#pragma unroll
    for (int nt = 0; nt < 4; ++nt) cbsv[nt] = cbs[cb0 + nt * 16];
#pragma unroll
    for (int mt = 0; mt < 4; ++mt)
#pragma unroll
      for (int r = 0; r < 4; ++r) {
        float d = fmaf(-2.0f, acc[mt][0][r], cbsv[0]);
        unsigned cidx = (unsigned)cb0;
#pragma unroll
        for (int nt = 1; nt < 4; ++nt) {
          float dn = fmaf(-2.0f, acc[mt][nt][r], cbsv[nt]);
          if (dn < d) { d = dn; cidx = (unsigned)(cb0 + nt * 16); }  // strict <: first-index ties
        }
        int ri = mt * 4 + r;
        if (d < rd[ri]) { rd[ri] = d; rc[ri] = cidx; }
      }
  }

  // Cross-lane (16 codes) then cross-wave (2 col-halves) reduce.
#pragma unroll
  for (int ri = 0; ri < 16; ++ri) {
    float d = rd[ri]; unsigned cidx = rc[ri];
#pragma unroll
    for (int off = 1; off < 16; off <<= 1) {
      float od = __shfl_xor(d, off);
      unsigned oc = __shfl_xor(cidx, off);
      if (od < d || (od == d && oc < cidx)) { d = od; cidx = oc; }
    }
    if (q == 0) {
      int row = wrow + (ri >> 2) * 16 + quad * 4 + (ri & 3);
      redD[w & 1][row] = d;
      redC[w & 1][row] = cidx;
    }
  }
  __syncthreads();
  if (tid < 128) {
    float d0 = redD[0][tid]; unsigned cc0 = redC[0][tid];
    float d1 = redD[1][tid]; unsigned cc1 = redC[1][tid];
    if (d1 < d0 || (d1 == d0 && cc1 < cc0)) { d0 = d1; cc0 = cc1; }
    unsigned u = __float_as_uint(d0);
    u = (u & 0x80000000u) ? ~u : (u | 0x80000000u);  // orderable float
    partials[(size_t)split * N_Q + q0 + tid] = ((unsigned long long)u << 32) | cc0;
  }
}

// ---------------- final: combine splits, write INT32 indices ----------------
__global__ void vq_final(const unsigned long long* __restrict__ partials,
                         int* __restrict__ out) {
  int i = blockIdx.x * 256 + threadIdx.x;  // 32768
  unsigned long long a = partials[i], b = partials[(size_t)N_Q + i];
  unsigned long long m = (b < a) ? b : a;  // equal dist -> lower code (low 32b)
  out[i] = (int)(unsigned)(m & 0xffffffffull);
}

extern "C" void kernel_launch(void* const* d_in, const int* in_sizes, int n_in,
                              void* d_out, int out_size, void* d_ws, size_t ws_size,
                              hipStream_t stream) {
  const float* z  = (const float*)d_in[0];   // [32,32,32,256] fp32
  const float* cb = (const float*)d_in[1];   // [8192,256] fp32
  char* ws = (char*)d_ws;
  // ws layout (~40.6 MB): zh 16M | zl 16M | eh 4M | el 4M | cbs 32K | partials 512K
  _Float16* zh = (_Float16*)(ws);
  _Float16* zl = (_Float16*)(ws + (size_t)16 * 1024 * 1024);
  _Float16* eh = (_Float16*)(ws + (size_t)32 * 1024 * 1024);
  _Float16* el = (_Float16*)(ws + (size_t)36 * 1024 * 1024);
  float*    cbs = (float*)(ws + (size_t)40 * 1024 * 1024);
  unsigned long long* partials =
      (unsigned long long*)(ws + (size_t)40 * 1024 * 1024 + 65536);

  hipLaunchKernelGGL(vq_prep_z,  dim3(8192), dim3(256), 0, stream, z, zh, zl);
  hipLaunchKernelGGL(vq_prep_cb, dim3(2048), dim3(256), 0, stream, cb, eh, el, cbs);
  hipLaunchKernelGGL(vq_main,    dim3(512),  dim3(256), 0, stream,
                     zh, zl, eh, el, cbs, partials);
  hipLaunchKernelGGL(vq_final,   dim3(128),  dim3(256), 0, stream,
                     partials, (int*)d_out);
}